// Round 9
// baseline (163.434 us; speedup 1.0000x reference)
//
#include <hip/hip_runtime.h>
#include <cstdint>
#include <cstddef>

typedef _Float16 f16x8 __attribute__((ext_vector_type(8)));
typedef _Float16 f16x4 __attribute__((ext_vector_type(4)));
typedef float f32x4 __attribute__((ext_vector_type(4)));

__device__ __forceinline__ void gload_lds16(const _Float16* g, void* l) {
  // async global->LDS, 16B/lane; LDS dest = wave-uniform base + lane*16
  __builtin_amdgcn_global_load_lds(
      (const __attribute__((address_space(1))) void*)(g),
      (__attribute__((address_space(3))) void*)(l), 16, 0, 0);
}

struct GDesc {
  const _Float16* A;  // [M][K] row-major, lda
  const _Float16* B;  // [N][K] row-major, ldb
  void* C;            // [M][N] row-major, ldc
  int lda, ldb, ldc, nbm, nbn;
};

#define MFMA16(d, va, vb) \
  d = __builtin_amdgcn_mfma_f32_16x16x32_f16(va, vb, d, 0, 0, 0)

// ---------------------------------------------------------------------------
// R9: faithful m201 8-phase template port. 256x256 NT GEMM, BK=64 stored as
// TWO BK=32 panels (panel = [256 rows][32 cols] f16, 16KB, row stride 64B,
// R2-verified zero-conflict XOR swizzle per panel). LDS = 2 buffers x 64KB:
//   buffer c at c*65536: A_p0 | A_p1 (+16384) | B_p0 (+32768) | B_p1 (+49152)
// 8 waves (2M x 4N), per-wave 128x64 out. Per K-tile: 4 phases, each
//   { ds_reads (4-8, THIS phase's frags) ; stage 1 panel of tile t+1
//     (2 gloads) ; s_barrier ; lgkmcnt(0) ; setprio1 ; 16 MFMA ; setprio0 ;
//     [end ph1/ph3: vmcnt(4)] ; s_barrier }
// vmcnt(4) ledger (2 gloads/panel, stage order A_p0,B_p0,A_p1,B_p1):
//   end-ph1(t): outstanding {A_p1(t),B_p1(t),A_p0(t+1),B_p0(t+1)}=8 ->
//     drains A_p1(t),B_p1(t) (read by ph2/ph3); barrier = cross-wave.
//   end-ph3(t): outstanding {4 panels of t+1}=8 -> drains A_p0,B_p0(t+1)
//     (read by t+1 ph0/ph1). Never <4 in flight; never drained to 0.
// lgkmcnt(0) per phase => no dangling LDS reads => 2-buffer WAR is sound
// (staging into buf (t+1)&1 happens after tile t-1's final barrier).
// Tail: t=nKT-1 re-stages tile nKT-1 into the dead buffer (ledger-neutral).
// ---------------------------------------------------------------------------
template <typename CT, bool MULTI>
__global__ __launch_bounds__(512, 2) void gemmq(
    GDesc d0, GDesc d1, GDesc d2,
    int inner, int nKT, int ksOff, size_t cSplit) {
  __shared__ __align__(16) char smem[131072];

  const int bid = blockIdx.x;
  const int gi  = bid / inner;
  int ib        = bid % inner;

  GDesc d = d0;
  if (MULTI) { if (gi == 1) d = d1; else if (gi == 2) d = d2; }
  const _Float16* A = d.A;
  const _Float16* B = d.B;
  CT* C = (CT*)d.C;
  if (!MULTI) {
    A += (size_t)gi * ksOff;
    B += (size_t)gi * ksOff;
    C += (size_t)gi * cSplit;
  }
  const int lda = d.lda, ldb = d.ldb, ldc = d.ldc, nbn = d.nbn;

  // XCD-aware swizzle (inner % 8 == 0 for all launches)
  ib = (ib & 7) * (inner >> 3) + (ib >> 3);
  const int brow = (ib / nbn) << 8;
  const int bcol = (ib % nbn) << 8;

  const int tid = threadIdx.x;
  const int w   = tid >> 6;   // 0..7
  const int l   = tid & 63;
  const int wm  = w >> 2;     // 0..1
  const int wn  = w & 3;      // 0..3

  // staging (per panel, identical to verified BK=32 math): chunk = 16 rows x
  // 64B; wave w stages chunks {w, w+8}. lane l -> row l>>2, phys slot l&3;
  // pre-swizzled global col q = (l&3) ^ ((l>>3)&3).
  const int sRow = l >> 2;
  const int sCol = (((l & 3) ^ ((l >> 3) & 3)) << 3);
  const _Float16* gA0 = A + (size_t)(brow + (w << 4) + sRow) * lda + sCol;
  const _Float16* gA1 = A + (size_t)(brow + ((w + 8) << 4) + sRow) * lda + sCol;
  const _Float16* gB0 = B + (size_t)(bcol + (w << 4) + sRow) * ldb + sCol;
  const _Float16* gB1 = B + (size_t)(bcol + ((w + 8) << 4) + sRow) * ldb + sCol;

  // fragment read offsets within a panel (swizzled): frag row r=l&15,
  // kslot l>>4: byte = r*64 + ((l>>4) ^ ((r>>1)&3))*16
  const int axr = (l >> 1) & 3;
  const int fq  = ((l >> 4) ^ axr) << 4;
  const int aBase = (wm << 13) + ((l & 15) << 6) + fq;
  const int bBase = (wn << 12) + ((l & 15) << 6) + fq;

  f32x4 acc[8][4] = {};

  // prologue: stage tile 0's 4 panels, order A_p0, B_p0, A_p1, B_p1
  {
    char* nb = smem;
    gload_lds16(gA0 + 0,  nb + (w << 10));
    gload_lds16(gA1 + 0,  nb + ((w + 8) << 10));
    gload_lds16(gB0 + 0,  nb + 32768 + (w << 10));
    gload_lds16(gB1 + 0,  nb + 32768 + ((w + 8) << 10));
    gload_lds16(gA0 + 32, nb + 16384 + (w << 10));
    gload_lds16(gA1 + 32, nb + 16384 + ((w + 8) << 10));
    gload_lds16(gB0 + 32, nb + 49152 + (w << 10));
    gload_lds16(gB1 + 32, nb + 49152 + ((w + 8) << 10));
  }
  asm volatile("s_waitcnt vmcnt(4)" ::: "memory");  // A_p0(0), B_p0(0) landed
  __builtin_amdgcn_s_barrier();

  for (int t = 0; t < nKT; ++t) {
    const char* cb = smem + (t & 1) * 65536;
    char* nb = smem + ((t + 1) & 1) * 65536;
    const int jc = (t + 1 < nKT) ? t + 1 : nKT - 1;  // clamped tail
    const int kof = jc * 64;

    f16x8 bf[4], a0f[4], a4f[4];

    // ---- ph0: ks0, m0-3 ----
#pragma unroll
    for (int n = 0; n < 4; ++n) bf[n]  = *(const f16x8*)(cb + 32768 + bBase + (n << 10));
#pragma unroll
    for (int m = 0; m < 4; ++m) a0f[m] = *(const f16x8*)(cb + aBase + (m << 10));
    gload_lds16(gA0 + kof, nb + (w << 10));
    gload_lds16(gA1 + kof, nb + ((w + 8) << 10));
    __builtin_amdgcn_s_barrier();
    asm volatile("s_waitcnt lgkmcnt(0)" ::: "memory");
    __builtin_amdgcn_sched_barrier(0);
    __builtin_amdgcn_s_setprio(1);
#pragma unroll
    for (int m = 0; m < 4; ++m)
#pragma unroll
      for (int n = 0; n < 4; ++n) MFMA16(acc[m][n], a0f[m], bf[n]);
    __builtin_amdgcn_s_setprio(0);
    __builtin_amdgcn_s_barrier();

    // ---- ph1: ks0, m4-7 ----
#pragma unroll
    for (int m = 0; m < 4; ++m) a4f[m] = *(const f16x8*)(cb + aBase + ((m + 4) << 10));
    gload_lds16(gB0 + kof, nb + 32768 + (w << 10));
    gload_lds16(gB1 + kof, nb + 32768 + ((w + 8) << 10));
    __builtin_amdgcn_s_barrier();
    asm volatile("s_waitcnt lgkmcnt(0)" ::: "memory");
    __builtin_amdgcn_sched_barrier(0);
    __builtin_amdgcn_s_setprio(1);
#pragma unroll
    for (int m = 0; m < 4; ++m)
#pragma unroll
      for (int n = 0; n < 4; ++n) MFMA16(acc[m + 4][n], a4f[m], bf[n]);
    __builtin_amdgcn_s_setprio(0);
    asm volatile("s_waitcnt vmcnt(4)" ::: "memory");  // A_p1(t), B_p1(t) landed
    __builtin_amdgcn_s_barrier();

    // ---- ph2: ks1, m0-3 ----
#pragma unroll
    for (int n = 0; n < 4; ++n) bf[n]  = *(const f16x8*)(cb + 49152 + bBase + (n << 10));
#pragma unroll
    for (int m = 0; m < 4; ++m) a0f[m] = *(const f16x8*)(cb + 16384 + aBase + (m << 10));
    gload_lds16(gA0 + kof + 32, nb + 16384 + (w << 10));
    gload_lds16(gA1 + kof + 32, nb + 16384 + ((w + 8) << 10));
    __builtin_amdgcn_s_barrier();
    asm volatile("s_waitcnt lgkmcnt(0)" ::: "memory");
    __builtin_amdgcn_sched_barrier(0);
    __builtin_amdgcn_s_setprio(1);
#pragma unroll
    for (int m = 0; m < 4; ++m)
#pragma unroll
      for (int n = 0; n < 4; ++n) MFMA16(acc[m][n], a0f[m], bf[n]);
    __builtin_amdgcn_s_setprio(0);
    __builtin_amdgcn_s_barrier();

    // ---- ph3: ks1, m4-7 ----
#pragma unroll
    for (int m = 0; m < 4; ++m) a4f[m] = *(const f16x8*)(cb + 16384 + aBase + ((m + 4) << 10));
    gload_lds16(gB0 + kof + 32, nb + 49152 + (w << 10));
    gload_lds16(gB1 + kof + 32, nb + 49152 + ((w + 8) << 10));
    __builtin_amdgcn_s_barrier();
    asm volatile("s_waitcnt lgkmcnt(0)" ::: "memory");
    __builtin_amdgcn_sched_barrier(0);
    __builtin_amdgcn_s_setprio(1);
#pragma unroll
    for (int m = 0; m < 4; ++m)
#pragma unroll
      for (int n = 0; n < 4; ++n) MFMA16(acc[m + 4][n], a4f[m], bf[n]);
    __builtin_amdgcn_s_setprio(0);
    asm volatile("s_waitcnt vmcnt(4)" ::: "memory");  // A_p0(t+1), B_p0(t+1) landed
    __builtin_amdgcn_s_barrier();
  }
  asm volatile("s_waitcnt vmcnt(0) lgkmcnt(0)" ::: "memory");

  // epilogue: C/D layout col=lane&15, row=(lane>>4)*4+jj
  const int crow0 = brow + (wm << 7) + ((l >> 4) << 2);
  const int ccol  = bcol + (wn << 6) + (l & 15);
#pragma unroll
  for (int m = 0; m < 8; ++m)
#pragma unroll
    for (int n = 0; n < 4; ++n)
#pragma unroll
      for (int jj = 0; jj < 4; ++jj)
        C[(size_t)(crow0 + (m << 4) + jj) * ldc + ccol + (n << 4)] = (CT)acc[m][n][jj];
}

// Row softmax: S[row, 0..N) f32 -> P fp16.
__global__ __launch_bounds__(256) void softmax_rows(const float* __restrict__ S,
                                                    _Float16* __restrict__ P,
                                                    int N) {
  __shared__ float buf[4096];
  __shared__ float red[8];
  const int row = blockIdx.x;
  const int tid = threadIdx.x;
  const int n4  = N >> 2;
  const float4* s4 = (const float4*)(S + (size_t)row * N);
  float4* b4 = (float4*)buf;

  float m = -3.4e38f;
  for (int i = tid; i < n4; i += 256) {
    float4 v = s4[i];
    b4[i] = v;
    m = fmaxf(m, fmaxf(fmaxf(v.x, v.y), fmaxf(v.z, v.w)));
  }
  for (int off = 32; off > 0; off >>= 1) m = fmaxf(m, __shfl_xor(m, off));
  if ((tid & 63) == 0) red[tid >> 6] = m;
  __syncthreads();
  m = fmaxf(fmaxf(red[0], red[1]), fmaxf(red[2], red[3]));

  float sum = 0.f;
  for (int i = tid; i < n4; i += 256) {
    float4 v = b4[i];
    v.x = __expf(v.x - m); v.y = __expf(v.y - m);
    v.z = __expf(v.z - m); v.w = __expf(v.w - m);
    b4[i] = v;
    sum += (v.x + v.y) + (v.z + v.w);
  }
  for (int off = 32; off > 0; off >>= 1) sum += __shfl_xor(sum, off);
  if ((tid & 63) == 0) red[4 + (tid >> 6)] = sum;
  __syncthreads();
  sum = (red[4] + red[5]) + (red[6] + red[7]);
  const float inv = 1.f / sum;

  f16x4* p4 = (f16x4*)(P + (size_t)row * N);
  for (int i = tid; i < n4; i += 256) {
    float4 v = b4[i];
    f16x4 h = { (_Float16)(v.x * inv), (_Float16)(v.y * inv),
                (_Float16)(v.z * inv), (_Float16)(v.w * inv) };
    p4[i] = h;
  }
}

__global__ __launch_bounds__(256) void cast_f32_f16(const float* __restrict__ in,
                                                    _Float16* __restrict__ out, int n4) {
  int i = blockIdx.x * 256 + threadIdx.x;
  if (i < n4) {
    float4 v = ((const float4*)in)[i];
    f16x4 h = { (_Float16)v.x, (_Float16)v.y, (_Float16)v.z, (_Float16)v.w };
    ((f16x4*)out)[i] = h;
  }
}

// out[i] = sum of 4 split-K partials (deterministic)
__global__ __launch_bounds__(256) void reduce4(const float* __restrict__ p,
                                               float* __restrict__ out,
                                               int n4, size_t stride4) {
  int i = blockIdx.x * 256 + threadIdx.x;
  if (i >= n4) return;
  const float4* p4 = (const float4*)p;
  float4 a = p4[i];
  float4 b = p4[i + stride4];
  float4 c = p4[i + 2 * stride4];
  float4 d = p4[i + 3 * stride4];
  float4 r = { (a.x + b.x) + (c.x + d.x), (a.y + b.y) + (c.y + d.y),
               (a.z + b.z) + (c.z + d.z), (a.w + b.w) + (c.w + d.w) };
  ((float4*)out)[i] = r;
}

extern "C" void kernel_launch(void* const* d_in, const int* in_sizes, int n_in,
                              void* d_out, int out_size, void* d_ws, size_t ws_size,
                              hipStream_t stream) {
  const int D  = 1024;
  const int N1 = in_sizes[0] / D;   // 4096
  const int N2 = in_sizes[1] / D;   // 4096

  const float* x1 = (const float*)d_in[0];
  const float* x2 = (const float*)d_in[1];
  const float* Wq = (const float*)d_in[2];
  const float* Wk = (const float*)d_in[3];
  const float* Wv = (const float*)d_in[4];
  float* out = (float*)d_out;

  _Float16* x1h = (_Float16*)d_ws;
  _Float16* x2h = x1h + (size_t)N1 * D;
  _Float16* Wqh = x2h + (size_t)N2 * D;
  _Float16* Wkh = Wqh + (size_t)D * D;
  _Float16* Wvh = Wkh + (size_t)D * D;
  _Float16* Qh  = Wvh + (size_t)D * D;
  _Float16* Kh  = Qh  + (size_t)N1 * D;
  _Float16* Vt  = Kh  + (size_t)N2 * D;   // Vt[j,i] = V[i,j]
  _Float16* P   = Vt  + (size_t)D * N2;
  float*    S   = (float*)(P + (size_t)N1 * N2);  // 64MB; reused as PV partials

  auto cast = [&](const float* src, _Float16* dst, size_t n) {
    int n4 = (int)(n >> 2);
    cast_f32_f16<<<dim3((n4 + 255) / 256), 256, 0, stream>>>(src, dst, n4);
  };
  cast(x1, x1h, (size_t)N1 * D);
  cast(x2, x2h, (size_t)N2 * D);
  cast(Wq, Wqh, (size_t)D * D);
  cast(Wk, Wkh, (size_t)D * D);
  cast(Wv, Wvh, (size_t)D * D);

  // Fused QKV projections: one 192-block dispatch, 64 blocks per GEMM.
  {
    GDesc dq = { x1h, Wqh, Qh, D, D, D, N1 / 256, D / 256 };
    GDesc dk = { x2h, Wkh, Kh, D, D, D, N2 / 256, D / 256 };
    GDesc dv = { Wvh, x2h, Vt, D, D, N2, D / 256, N2 / 256 };
    gemmq<_Float16, true><<<dim3(192), 512, 0, stream>>>(dq, dk, dv, 64, D / 64, 0, 0);
  }
  // S = Q K^T [4096x4096] f32, grid 256 (1 block/CU)
  {
    GDesc dsd = { Qh, Kh, S, D, D, N2, N1 / 256, N2 / 256 };
    gemmq<float, false><<<dim3(256), 512, 0, stream>>>(dsd, dsd, dsd, 256, D / 64, 0, 0);
  }
  // P = softmax(S)
  softmax_rows<<<dim3(N1), 256, 0, stream>>>(S, P, N2);
  // PV split-K=4: partial[s] = P[:, s*1024:+1024] @ Vt[:, s*1024:+1024]^T
  {
    GDesc dp = { P, Vt, S, N2, N2, D, N1 / 256, D / 256 };
    gemmq<float, false><<<dim3(256), 512, 0, stream>>>(dp, dp, dp, 64, 1024 / 64, 1024,
                                                       (size_t)N1 * D);
  }
  reduce4<<<dim3((N1 * D / 4 + 255) / 256), 256, 0, stream>>>(
      S, out, N1 * D / 4, (size_t)N1 * D / 4);
}

// Round 10
// 143.505 us; speedup vs baseline: 1.1389x; 1.1389x over previous
//
#include <hip/hip_runtime.h>
#include <cstdint>
#include <cstddef>

typedef _Float16 f16x8 __attribute__((ext_vector_type(8)));
typedef _Float16 f16x4 __attribute__((ext_vector_type(4)));
typedef float f32x4 __attribute__((ext_vector_type(4)));

__device__ __forceinline__ void gload_lds16(const _Float16* g, void* l) {
  // async global->LDS, 16B/lane; LDS dest = wave-uniform base + lane*16
  __builtin_amdgcn_global_load_lds(
      (const __attribute__((address_space(1))) void*)(g),
      (__attribute__((address_space(3))) void*)(l), 16, 0, 0);
}

struct GDesc {
  const _Float16* A;  // [M][K] row-major, lda
  const _Float16* B;  // [N][K] row-major, ldb
  void* C;            // [M][N] row-major, ldc
  int lda, ldb, ldc, nbm, nbn;
};

#define MFMA16(d, va, vb) \
  d = __builtin_amdgcn_mfma_f32_16x16x32_f16(va, vb, d, 0, 0, 0)

// ---------------------------------------------------------------------------
// R9 gemmq (passing, ~815 TF/block-loop): 256x256 NT GEMM, BK=64 as two BK=32
// panels, 2 LDS buffers x 64KB, 8 waves (2M x 4N), 4 phases/K-tile each
// { ds_reads ; 2 gloads ; barrier ; lgkmcnt(0) ; setprio+16 MFMA ;
//   [end ph1/ph3: vmcnt(4)] ; barrier }.
// Zero-conflict XOR swizzle (R2-R9 verified, SQ_LDS_BANK_CONFLICT=0).
// UNCHANGED this round (5 schedule variants all ~42 us; plateau accepted).
// ---------------------------------------------------------------------------
template <typename CT, bool MULTI>
__global__ __launch_bounds__(512, 2) void gemmq(
    GDesc d0, GDesc d1, GDesc d2,
    int inner, int nKT, int ksOff, size_t cSplit) {
  __shared__ __align__(16) char smem[131072];

  const int bid = blockIdx.x;
  const int gi  = bid / inner;
  int ib        = bid % inner;

  GDesc d = d0;
  if (MULTI) { if (gi == 1) d = d1; else if (gi == 2) d = d2; }
  const _Float16* A = d.A;
  const _Float16* B = d.B;
  CT* C = (CT*)d.C;
  if (!MULTI) {
    A += (size_t)gi * ksOff;
    B += (size_t)gi * ksOff;
    C += (size_t)gi * cSplit;
  }
  const int lda = d.lda, ldb = d.ldb, ldc = d.ldc, nbn = d.nbn;

  // XCD-aware swizzle (inner % 8 == 0 for all launches)
  ib = (ib & 7) * (inner >> 3) + (ib >> 3);
  const int brow = (ib / nbn) << 8;
  const int bcol = (ib % nbn) << 8;

  const int tid = threadIdx.x;
  const int w   = tid >> 6;   // 0..7
  const int l   = tid & 63;
  const int wm  = w >> 2;     // 0..1
  const int wn  = w & 3;      // 0..3

  const int sRow = l >> 2;
  const int sCol = (((l & 3) ^ ((l >> 3) & 3)) << 3);
  const _Float16* gA0 = A + (size_t)(brow + (w << 4) + sRow) * lda + sCol;
  const _Float16* gA1 = A + (size_t)(brow + ((w + 8) << 4) + sRow) * lda + sCol;
  const _Float16* gB0 = B + (size_t)(bcol + (w << 4) + sRow) * ldb + sCol;
  const _Float16* gB1 = B + (size_t)(bcol + ((w + 8) << 4) + sRow) * ldb + sCol;

  const int axr = (l >> 1) & 3;
  const int fq  = ((l >> 4) ^ axr) << 4;
  const int aBase = (wm << 13) + ((l & 15) << 6) + fq;
  const int bBase = (wn << 12) + ((l & 15) << 6) + fq;

  f32x4 acc[8][4] = {};

  // prologue: stage tile 0's 4 panels, order A_p0, B_p0, A_p1, B_p1
  {
    char* nb = smem;
    gload_lds16(gA0 + 0,  nb + (w << 10));
    gload_lds16(gA1 + 0,  nb + ((w + 8) << 10));
    gload_lds16(gB0 + 0,  nb + 32768 + (w << 10));
    gload_lds16(gB1 + 0,  nb + 32768 + ((w + 8) << 10));
    gload_lds16(gA0 + 32, nb + 16384 + (w << 10));
    gload_lds16(gA1 + 32, nb + 16384 + ((w + 8) << 10));
    gload_lds16(gB0 + 32, nb + 49152 + (w << 10));
    gload_lds16(gB1 + 32, nb + 49152 + ((w + 8) << 10));
  }
  asm volatile("s_waitcnt vmcnt(4)" ::: "memory");
  __builtin_amdgcn_s_barrier();

  for (int t = 0; t < nKT; ++t) {
    const char* cb = smem + (t & 1) * 65536;
    char* nb = smem + ((t + 1) & 1) * 65536;
    const int jc = (t + 1 < nKT) ? t + 1 : nKT - 1;  // clamped tail
    const int kof = jc * 64;

    f16x8 bf[4], a0f[4], a4f[4];

    // ---- ph0: ks0, m0-3 ----
#pragma unroll
    for (int n = 0; n < 4; ++n) bf[n]  = *(const f16x8*)(cb + 32768 + bBase + (n << 10));
#pragma unroll
    for (int m = 0; m < 4; ++m) a0f[m] = *(const f16x8*)(cb + aBase + (m << 10));
    gload_lds16(gA0 + kof, nb + (w << 10));
    gload_lds16(gA1 + kof, nb + ((w + 8) << 10));
    __builtin_amdgcn_s_barrier();
    asm volatile("s_waitcnt lgkmcnt(0)" ::: "memory");
    __builtin_amdgcn_sched_barrier(0);
    __builtin_amdgcn_s_setprio(1);
#pragma unroll
    for (int m = 0; m < 4; ++m)
#pragma unroll
      for (int n = 0; n < 4; ++n) MFMA16(acc[m][n], a0f[m], bf[n]);
    __builtin_amdgcn_s_setprio(0);
    __builtin_amdgcn_s_barrier();

    // ---- ph1: ks0, m4-7 ----
#pragma unroll
    for (int m = 0; m < 4; ++m) a4f[m] = *(const f16x8*)(cb + aBase + ((m + 4) << 10));
    gload_lds16(gB0 + kof, nb + 32768 + (w << 10));
    gload_lds16(gB1 + kof, nb + 32768 + ((w + 8) << 10));
    __builtin_amdgcn_s_barrier();
    asm volatile("s_waitcnt lgkmcnt(0)" ::: "memory");
    __builtin_amdgcn_sched_barrier(0);
    __builtin_amdgcn_s_setprio(1);
#pragma unroll
    for (int m = 0; m < 4; ++m)
#pragma unroll
      for (int n = 0; n < 4; ++n) MFMA16(acc[m + 4][n], a4f[m], bf[n]);
    __builtin_amdgcn_s_setprio(0);
    asm volatile("s_waitcnt vmcnt(4)" ::: "memory");
    __builtin_amdgcn_s_barrier();

    // ---- ph2: ks1, m0-3 ----
#pragma unroll
    for (int n = 0; n < 4; ++n) bf[n]  = *(const f16x8*)(cb + 49152 + bBase + (n << 10));
#pragma unroll
    for (int m = 0; m < 4; ++m) a0f[m] = *(const f16x8*)(cb + 16384 + aBase + (m << 10));
    gload_lds16(gA0 + kof + 32, nb + 16384 + (w << 10));
    gload_lds16(gA1 + kof + 32, nb + 16384 + ((w + 8) << 10));
    __builtin_amdgcn_s_barrier();
    asm volatile("s_waitcnt lgkmcnt(0)" ::: "memory");
    __builtin_amdgcn_sched_barrier(0);
    __builtin_amdgcn_s_setprio(1);
#pragma unroll
    for (int m = 0; m < 4; ++m)
#pragma unroll
      for (int n = 0; n < 4; ++n) MFMA16(acc[m][n], a0f[m], bf[n]);
    __builtin_amdgcn_s_setprio(0);
    __builtin_amdgcn_s_barrier();

    // ---- ph3: ks1, m4-7 ----
#pragma unroll
    for (int m = 0; m < 4; ++m) a4f[m] = *(const f16x8*)(cb + 16384 + aBase + ((m + 4) << 10));
    gload_lds16(gB0 + kof + 32, nb + 49152 + (w << 10));
    gload_lds16(gB1 + kof + 32, nb + 49152 + ((w + 8) << 10));
    __builtin_amdgcn_s_barrier();
    asm volatile("s_waitcnt lgkmcnt(0)" ::: "memory");
    __builtin_amdgcn_sched_barrier(0);
    __builtin_amdgcn_s_setprio(1);
#pragma unroll
    for (int m = 0; m < 4; ++m)
#pragma unroll
      for (int n = 0; n < 4; ++n) MFMA16(acc[m + 4][n], a4f[m], bf[n]);
    __builtin_amdgcn_s_setprio(0);
    asm volatile("s_waitcnt vmcnt(4)" ::: "memory");
    __builtin_amdgcn_s_barrier();
  }
  asm volatile("s_waitcnt vmcnt(0) lgkmcnt(0)" ::: "memory");

  // epilogue: C/D layout col=lane&15, row=(lane>>4)*4+jj
  const int crow0 = brow + (wm << 7) + ((l >> 4) << 2);
  const int ccol  = bcol + (wn << 6) + (l & 15);
#pragma unroll
  for (int m = 0; m < 8; ++m)
#pragma unroll
    for (int n = 0; n < 4; ++n)
#pragma unroll
      for (int jj = 0; jj < 4; ++jj)
        C[(size_t)(crow0 + (m << 4) + jj) * ldc + ccol + (n << 4)] = (CT)acc[m][n][jj];
}

// Row softmax: S[row, 0..N) fp16 -> P fp16 (internal f32).
__global__ __launch_bounds__(256) void softmax_rows(const _Float16* __restrict__ S,
                                                    _Float16* __restrict__ P,
                                                    int N) {
  __shared__ float buf[4096];
  __shared__ float red[8];
  const int row = blockIdx.x;
  const int tid = threadIdx.x;
  const int n8  = N >> 3;
  const int n4  = N >> 2;
  const f16x8* s8 = (const f16x8*)(S + (size_t)row * N);
  float4* b4 = (float4*)buf;

  float m = -3.4e38f;
  for (int i = tid; i < n8; i += 256) {
    f16x8 v = s8[i];
    float4 lo = { (float)v[0], (float)v[1], (float)v[2], (float)v[3] };
    float4 hi = { (float)v[4], (float)v[5], (float)v[6], (float)v[7] };
    b4[2 * i] = lo;
    b4[2 * i + 1] = hi;
    m = fmaxf(m, fmaxf(fmaxf(fmaxf(lo.x, lo.y), fmaxf(lo.z, lo.w)),
                       fmaxf(fmaxf(hi.x, hi.y), fmaxf(hi.z, hi.w))));
  }
  for (int off = 32; off > 0; off >>= 1) m = fmaxf(m, __shfl_xor(m, off));
  if ((tid & 63) == 0) red[tid >> 6] = m;
  __syncthreads();
  m = fmaxf(fmaxf(red[0], red[1]), fmaxf(red[2], red[3]));

  float sum = 0.f;
  for (int i = tid; i < n4; i += 256) {
    float4 v = b4[i];
    v.x = __expf(v.x - m); v.y = __expf(v.y - m);
    v.z = __expf(v.z - m); v.w = __expf(v.w - m);
    b4[i] = v;
    sum += (v.x + v.y) + (v.z + v.w);
  }
  for (int off = 32; off > 0; off >>= 1) sum += __shfl_xor(sum, off);
  if ((tid & 63) == 0) red[4 + (tid >> 6)] = sum;
  __syncthreads();
  sum = (red[4] + red[5]) + (red[6] + red[7]);
  const float inv = 1.f / sum;

  f16x4* p4 = (f16x4*)(P + (size_t)row * N);
  for (int i = tid; i < n4; i += 256) {
    float4 v = b4[i];
    f16x4 h = { (_Float16)(v.x * inv), (_Float16)(v.y * inv),
                (_Float16)(v.z * inv), (_Float16)(v.w * inv) };
    p4[i] = h;
  }
}

// One kernel for all 5 f32->fp16 casts. Destinations are contiguous in ws
// (x1h | x2h | Wqh | Wkh | Wvh); sources are the 5 input pointers.
__global__ __launch_bounds__(256) void cast_all(
    const float* __restrict__ x1, const float* __restrict__ x2,
    const float* __restrict__ wq, const float* __restrict__ wk,
    const float* __restrict__ wv, _Float16* __restrict__ dst,
    int nx4, int nw4) {  // nx4 = N*D/4 per x, nw4 = D*D/4 per W
  int i = blockIdx.x * 256 + threadIdx.x;
  const int total = 2 * nx4 + 3 * nw4;
  if (i >= total) return;
  const float* src;
  int off;
  if (i < nx4)           { src = x1; off = i; }
  else if (i < 2 * nx4)  { src = x2; off = i - nx4; }
  else {
    int j = i - 2 * nx4;
    if (j < nw4)           { src = wq; off = j; }
    else if (j < 2 * nw4)  { src = wk; off = j - nw4; }
    else                   { src = wv; off = j - 2 * nw4; }
  }
  float4 v = ((const float4*)src)[off];
  f16x4 h = { (_Float16)v.x, (_Float16)v.y, (_Float16)v.z, (_Float16)v.w };
  ((f16x4*)dst)[i] = h;
}

// out[i] = sum of 4 fp16 split-K partials (deterministic, f32 accumulate)
__global__ __launch_bounds__(256) void reduce4(const _Float16* __restrict__ p,
                                               float* __restrict__ out,
                                               int n4, size_t stride4) {
  int i = blockIdx.x * 256 + threadIdx.x;
  if (i >= n4) return;
  const f16x4* p4 = (const f16x4*)p;
  f16x4 a = p4[i];
  f16x4 b = p4[i + stride4];
  f16x4 c = p4[i + 2 * stride4];
  f16x4 d = p4[i + 3 * stride4];
  float4 r = { ((float)a[0] + (float)b[0]) + ((float)c[0] + (float)d[0]),
               ((float)a[1] + (float)b[1]) + ((float)c[1] + (float)d[1]),
               ((float)a[2] + (float)b[2]) + ((float)c[2] + (float)d[2]),
               ((float)a[3] + (float)b[3]) + ((float)c[3] + (float)d[3]) };
  ((float4*)out)[i] = r;
}

extern "C" void kernel_launch(void* const* d_in, const int* in_sizes, int n_in,
                              void* d_out, int out_size, void* d_ws, size_t ws_size,
                              hipStream_t stream) {
  const int D  = 1024;
  const int N1 = in_sizes[0] / D;   // 4096
  const int N2 = in_sizes[1] / D;   // 4096

  const float* x1 = (const float*)d_in[0];
  const float* x2 = (const float*)d_in[1];
  const float* Wq = (const float*)d_in[2];
  const float* Wk = (const float*)d_in[3];
  const float* Wv = (const float*)d_in[4];
  float* out = (float*)d_out;

  _Float16* x1h = (_Float16*)d_ws;
  _Float16* x2h = x1h + (size_t)N1 * D;
  _Float16* Wqh = x2h + (size_t)N2 * D;
  _Float16* Wkh = Wqh + (size_t)D * D;
  _Float16* Wvh = Wkh + (size_t)D * D;
  _Float16* Qh  = Wvh + (size_t)D * D;
  _Float16* Kh  = Qh  + (size_t)N1 * D;
  _Float16* Vt  = Kh  + (size_t)N2 * D;   // Vt[j,i] = V[i,j]
  _Float16* P   = Vt  + (size_t)D * N2;
  _Float16* S   = P   + (size_t)N1 * N2;  // fp16 S (32MB); reused as PV partials

  // all casts in one dispatch (dst regions contiguous: x1h..Wvh)
  {
    int nx4 = N1 * D / 4;          // 1,048,576 (x1 == x2 size here)
    int nw4 = D * D / 4;           // 262,144
    int total = 2 * nx4 + 3 * nw4;
    cast_all<<<dim3((total + 255) / 256), 256, 0, stream>>>(
        x1, x2, Wq, Wk, Wv, x1h, nx4, nw4);
  }

  // Fused QKV projections: one 192-block dispatch, 64 blocks per GEMM.
  {
    GDesc dq = { x1h, Wqh, Qh, D, D, D, N1 / 256, D / 256 };
    GDesc dk = { x2h, Wkh, Kh, D, D, D, N2 / 256, D / 256 };
    GDesc dv = { Wvh, x2h, Vt, D, D, N2, D / 256, N2 / 256 };
    gemmq<_Float16, true><<<dim3(192), 512, 0, stream>>>(dq, dk, dv, 64, D / 64, 0, 0);
  }
  // S = Q K^T [4096x4096] fp16 out, grid 256 (1 block/CU)
  {
    GDesc dsd = { Qh, Kh, S, D, D, N2, N1 / 256, N2 / 256 };
    gemmq<_Float16, false><<<dim3(256), 512, 0, stream>>>(dsd, dsd, dsd, 256, D / 64, 0, 0);
  }
  // P = softmax(S)
  softmax_rows<<<dim3(N1), 256, 0, stream>>>(S, P, N2);
  // PV split-K=4: fp16 partial[s] = P[:, s*1024:+1024] @ Vt[:, s*1024:+1024]^T
  {
    GDesc dp = { P, Vt, S, N2, N2, D, N1 / 256, D / 256 };
    gemmq<_Float16, false><<<dim3(256), 512, 0, stream>>>(dp, dp, dp, 64, 1024 / 64, 1024,
                                                          (size_t)N1 * D);
  }
  reduce4<<<dim3((N1 * D / 4 + 255) / 256), 256, 0, stream>>>(
      S, out, N1 * D / 4, (size_t)N1 * D / 4);
}